// Round 1
// baseline (347.470 us; speedup 1.0000x reference)
//
#include <hip/hip_runtime.h>
#include <stdint.h>

// TopKMS (OHEM top-k MSE): per-row MSE over [N, 512] fp32, mean of top-30% rows.
// Strategy: one pass over the 256 MB inputs computing row MSE (one wave/row),
// binning each row value into a bit-pattern histogram (monotone for positive
// floats, so no min/max pre-pass); then a single-block scan finds the rank-k
// cutoff bin and forms the top-k mean from per-bin (count, sum).

#define D_FEAT 512
#define ROWS_PER_BLOCK 4
#define SCAN_THREADS 256

__global__ __launch_bounds__(256) void zero_ws_kernel(int* __restrict__ ws, int n) {
    int i = blockIdx.x * blockDim.x + threadIdx.x;
    if (i < n) ws[i] = 0;
}

__global__ __launch_bounds__(256) void mse_hist_kernel(
    const float* __restrict__ input,
    const float* __restrict__ target,
    int n_rows,
    int* __restrict__ cnt_hist,
    float* __restrict__ sum_hist,
    int shift, int base, int nbins)
{
    const int wave = threadIdx.x >> 6;
    const int lane = threadIdx.x & 63;
    const int row  = blockIdx.x * ROWS_PER_BLOCK + wave;
    if (row >= n_rows) return;

    // 512 floats/row = 128 float4; 64 lanes x 2 float4 each, fully coalesced.
    const float4* __restrict__ a = (const float4*)(input  + (size_t)row * D_FEAT);
    const float4* __restrict__ b = (const float4*)(target + (size_t)row * D_FEAT);

    float4 a0 = a[lane];
    float4 b0 = b[lane];
    float4 a1 = a[lane + 64];
    float4 b1 = b[lane + 64];

    float acc = 0.0f, d;
    d = a0.x - b0.x; acc += d * d;
    d = a0.y - b0.y; acc += d * d;
    d = a0.z - b0.z; acc += d * d;
    d = a0.w - b0.w; acc += d * d;
    d = a1.x - b1.x; acc += d * d;
    d = a1.y - b1.y; acc += d * d;
    d = a1.z - b1.z; acc += d * d;
    d = a1.w - b1.w; acc += d * d;

    // wave-64 butterfly reduction
    #pragma unroll
    for (int off = 32; off > 0; off >>= 1)
        acc += __shfl_xor(acc, off, 64);

    if (lane == 0) {
        float v = acc * (1.0f / (float)D_FEAT);
        // positive float -> uint32 bit pattern is monotone; bin on high bits.
        uint32_t bits = __float_as_uint(v);
        int bin = (int)(bits >> shift) - base;
        bin = bin < 0 ? 0 : (bin > nbins - 1 ? nbins - 1 : bin);
        atomicAdd(&cnt_hist[bin], 1);
        atomicAdd(&sum_hist[bin], v);
    }
}

__global__ __launch_bounds__(SCAN_THREADS) void topk_from_hist_kernel(
    const int* __restrict__ cnt_hist,
    const float* __restrict__ sum_hist,
    int nbins, int k,
    float* __restrict__ out)
{
    const int t = threadIdx.x;
    const int ch = nbins / SCAN_THREADS;     // bins per thread
    const int start = nbins - 1 - t * ch;    // thread t owns a descending chunk

    int   c_t = 0;
    float s_t = 0.0f;
    for (int j = 0; j < ch; ++j) {
        int b = start - j;
        c_t += cnt_hist[b];
        s_t += sum_hist[b];
    }

    __shared__ int   cs[SCAN_THREADS];
    __shared__ float ss[SCAN_THREADS];
    cs[t] = c_t;
    ss[t] = s_t;
    __syncthreads();

    // Hillis-Steele inclusive scan over thread chunks (ordered top -> bottom)
    for (int off = 1; off < SCAN_THREADS; off <<= 1) {
        int cv = 0; float sv = 0.0f;
        if (t >= off) { cv = cs[t - off]; sv = ss[t - off]; }
        __syncthreads();
        cs[t] += cv;
        ss[t] += sv;
        __syncthreads();
    }

    const int   c_incl   = cs[t];
    const float s_incl   = ss[t];
    const int   c_before = c_incl - c_t;
    const float s_before = s_incl - s_t;

    // exactly one thread's chunk straddles rank k (total count == n_rows >= k)
    if (c_before < k && k <= c_incl) {
        int   cum = c_before;
        float s   = s_before;
        float result = 0.0f;
        for (int j = 0; j < ch; ++j) {
            int b = start - j;
            int c = cnt_hist[b];
            if (c == 0) continue;
            if (cum + c >= k) {
                int need = k - cum;
                float avg = sum_hist[b] / (float)c;   // bin mean: better than bin center
                result = (s + (float)need * avg) / (float)k;
                break;
            }
            cum += c;
            s   += sum_hist[b];
        }
        out[0] = result;
    }
}

extern "C" void kernel_launch(void* const* d_in, const int* in_sizes, int n_in,
                              void* d_out, int out_size, void* d_ws, size_t ws_size,
                              hipStream_t stream)
{
    const float* input  = (const float*)d_in[0];
    const float* target = (const float*)d_in[1];
    float* out = (float*)d_out;

    const int total  = in_sizes[0];
    const int n_rows = total / D_FEAT;            // 65536
    int k = (int)(0.3 * (double)n_rows);          // matches int(K_FRAC * n)
    if (k < 1) k = 1;
    if (k > n_rows) k = n_rows;

    // Histogram over float bit patterns, exponent range [2^-8, 2^8).
    // shift=13 -> 10 mantissa bits, 16384 bins (128 KB ws); fall back to
    // shift=16 -> 2048 bins (16 KB) if ws is small. Both are far inside the
    // 2% tolerance (bin rel-width 2^-10 / 2^-7).
    const int shift = (ws_size >= (size_t)(16384 * 8)) ? 13 : 16;
    const int mant_log2 = 23 - shift;
    const int nbins = 16 << mant_log2;
    const int base  = 119 << mant_log2;           // exponent field 119 == 2^-8

    int*   cnt_hist = (int*)d_ws;
    float* sum_hist = (float*)d_ws + nbins;

    const int zn = nbins * 2;                     // cnt + sum words (0 bits == 0.0f)
    zero_ws_kernel<<<(zn + 255) / 256, 256, 0, stream>>>((int*)d_ws, zn);

    const int grid = (n_rows + ROWS_PER_BLOCK - 1) / ROWS_PER_BLOCK;
    mse_hist_kernel<<<grid, 256, 0, stream>>>(input, target, n_rows,
                                              cnt_hist, sum_hist, shift, base, nbins);

    topk_from_hist_kernel<<<1, SCAN_THREADS, 0, stream>>>(cnt_hist, sum_hist, nbins, k, out);
}